// Round 1
// baseline (698.241 us; speedup 1.0000x reference)
//
#include <hip/hip_runtime.h>
#include <hip/hip_bf16.h>
#include <cstdint>

// Problem constants
#define S_FRAMES 128
#define HW       50176            // 224*224
#define GDIM     48
#define VWORDS   3456             // 48^3 / 32 bits
#define NBINS    4096
#define CAP      3072
#define KSEL     16

// workspace layout (in 32-bit words)
#define OCC_OFF   0u                          // 128 * 3456 words
#define COV_OFF   (128u*3456u)                // 3456 words
#define KEY_OFF   (COV_OFF + 3456u)           // 16 words
#define SEL_OFF   (KEY_OFF + 16u)             // 4 words (128-bit selected mask)
#define MAXU_OFF  (SEL_OFF + 4u)              // 3 words (encoded max, init 0x00)
#define MINU_OFF  (MAXU_OFF + 3u)             // 3 words (encoded min, init 0xFF)
#define PCT_OFF   (MINU_OFF + 3u)             // 128 floats

__device__ __forceinline__ unsigned fkey(float f) {
    unsigned u = __float_as_uint(f);
    return (u & 0x80000000u) ? ~u : (u | 0x80000000u);
}
__device__ __forceinline__ float funkey(unsigned k) {
    unsigned u = (k & 0x80000000u) ? (k & 0x7fffffffu) : ~k;
    return __uint_as_float(u);
}

// ---------------------------------------------------------------------------
// Pass A: exact per-frame median (jnp.quantile 0.5 linear) via histogram select
// grid: 128 blocks (one per frame), 256 threads
// ---------------------------------------------------------------------------
__global__ __launch_bounds__(256) void pct_kernel(const float* __restrict__ conf,
                                                  float* __restrict__ pct) {
    const int s = blockIdx.x;
    const int tid = threadIdx.x;
    const float* c = conf + (size_t)s * HW;

    __shared__ unsigned hist[NBINS];
    __shared__ unsigned ps[256];
    __shared__ float    list[CAP];
    __shared__ unsigned cnt;
    __shared__ int      rbin[2];
    __shared__ unsigned rcum[2];
    __shared__ float    ab[2];

    for (int b = tid; b < NBINS; b += 256) hist[b] = 0;
    if (tid == 0) cnt = 0;
    __syncthreads();

    for (int p = tid; p < HW; p += 256) {
        float v = c[p];
        int b = (int)(v * 4096.0f);
        b = min(max(b, 0), NBINS - 1);
        atomicAdd(&hist[b], 1u);
    }
    __syncthreads();

    // chunk sums + inclusive scan over 256 chunks of 16 bins
    unsigned chunk = 0;
#pragma unroll
    for (int j = 0; j < 16; j++) chunk += hist[tid * 16 + j];
    ps[tid] = chunk;
    __syncthreads();
    for (int off = 1; off < 256; off <<= 1) {
        unsigned v = (tid >= off) ? ps[tid - off] : 0u;
        __syncthreads();
        ps[tid] += v;
        __syncthreads();
    }
    unsigned excl = ps[tid] - chunk;

    const unsigned R0 = 25087u, R1 = 25088u;  // 0.5*(50176-1) = 25087.5
#pragma unroll
    for (int r = 0; r < 2; r++) {
        unsigned rr = r ? R1 : R0;
        if (rr >= excl && rr < excl + chunk) {
            unsigned cum = excl;
            for (int j = 0; j < 16; j++) {
                unsigned h = hist[tid * 16 + j];
                if (rr < cum + h) { rbin[r] = tid * 16 + j; rcum[r] = cum; break; }
                cum += h;
            }
        }
    }
    __syncthreads();

    const int blo = rbin[0], bhi = rbin[1];
    const unsigned cumLo = rcum[0];

    for (int p = tid; p < HW; p += 256) {
        float v = c[p];
        int b = (int)(v * 4096.0f);
        b = min(max(b, 0), NBINS - 1);
        if (b >= blo && b <= bhi) {
            unsigned pos = atomicAdd(&cnt, 1u);
            if (pos < CAP) list[pos] = v;
        }
    }
    __syncthreads();

    const int n = (int)min(cnt, (unsigned)CAP);
    const int r0 = (int)(R0 - cumLo), r1 = (int)(R1 - cumLo);
    for (int e = tid; e < n; e += 256) {
        float x = list[e];
        int rank = 0;
        for (int j = 0; j < n; j++) {
            float y = list[j];
            rank += (y < x) || (y == x && j < e);   // stable rank
        }
        if (rank == r0) ab[0] = x;
        if (rank == r1) ab[1] = x;
    }
    __syncthreads();
    if (tid == 0) pct[s] = 0.5f * ab[0] + 0.5f * ab[1];
}

// ---------------------------------------------------------------------------
// Pass B: global min/max over valid points. grid (7,128) blocks x 256 threads
// ---------------------------------------------------------------------------
__global__ __launch_bounds__(256) void minmax_kernel(const float* __restrict__ wp,
                                                     const float* __restrict__ conf,
                                                     const float* __restrict__ pct,
                                                     unsigned* __restrict__ ws) {
    const int s = blockIdx.y;
    const int part = blockIdx.x;
    const int tid = threadIdx.x;
    const float pc = pct[s];
    const size_t base = (size_t)s * HW;

    float mnx = 3.402823466e38f, mny = mnx, mnz = mnx;
    float mxx = -3.402823466e38f, mxy = mxx, mxz = mxx;

    const int p0 = part * 8192;
    for (int k = 0; k < 32; k++) {
        int p = p0 + k * 256 + tid;
        if (p >= HW) break;
        float cf = conf[base + p];
        if (cf > 0.1f && cf >= pc) {
            const float* q = wp + (base + (size_t)p) * 3;
            float x = q[0], y = q[1], z = q[2];
            mnx = fminf(mnx, x); mny = fminf(mny, y); mnz = fminf(mnz, z);
            mxx = fmaxf(mxx, x); mxy = fmaxf(mxy, y); mxz = fmaxf(mxz, z);
        }
    }
#pragma unroll
    for (int m = 32; m >= 1; m >>= 1) {
        mnx = fminf(mnx, __shfl_xor(mnx, m)); mny = fminf(mny, __shfl_xor(mny, m));
        mnz = fminf(mnz, __shfl_xor(mnz, m));
        mxx = fmaxf(mxx, __shfl_xor(mxx, m)); mxy = fmaxf(mxy, __shfl_xor(mxy, m));
        mxz = fmaxf(mxz, __shfl_xor(mxz, m));
    }
    if ((tid & 63) == 0) {
        atomicMin(ws + MINU_OFF + 0, fkey(mnx));
        atomicMin(ws + MINU_OFF + 1, fkey(mny));
        atomicMin(ws + MINU_OFF + 2, fkey(mnz));
        atomicMax(ws + MAXU_OFF + 0, fkey(mxx));
        atomicMax(ws + MAXU_OFF + 1, fkey(mxy));
        atomicMax(ws + MAXU_OFF + 2, fkey(mxz));
    }
}

// ---------------------------------------------------------------------------
// Pass C: per-frame voxel occupancy bitmaps. grid 512 (4 blocks/frame) x 256
// ---------------------------------------------------------------------------
__global__ __launch_bounds__(256) void voxel_kernel(const float* __restrict__ wp,
                                                    const float* __restrict__ conf,
                                                    const float* __restrict__ pct,
                                                    unsigned* __restrict__ ws) {
    const int bx = blockIdx.x;
    const int s = bx >> 2;
    const int part = bx & 3;
    const int tid = threadIdx.x;

    __shared__ unsigned bm[VWORDS];
    for (int w = tid; w < VWORDS; w += 256) bm[w] = 0;
    __syncthreads();

    const float pc = pct[s];
    const float pmx = funkey(ws[MINU_OFF + 0]);
    const float pmy = funkey(ws[MINU_OFF + 1]);
    const float pmz = funkey(ws[MINU_OFF + 2]);
    const float dx = funkey(ws[MAXU_OFF + 0]) - pmx;
    const float dy = funkey(ws[MAXU_OFF + 1]) - pmy;
    const float dz = funkey(ws[MAXU_OFF + 2]) - pmz;
    const float vs = fminf(dx, fminf(dy, dz)) / 20.0f;  // VOXEL_LAMBDA

    const size_t base = (size_t)s * HW;
    const int p0 = part * 12544;
#pragma unroll 1
    for (int k = 0; k < 49; k++) {
        int p = p0 + k * 256 + tid;
        float cf = conf[base + p];
        if (cf > 0.1f && cf >= pc) {
            const float* q = wp + (base + (size_t)p) * 3;
            int ix = (int)floorf((q[0] - pmx) / vs); ix = min(max(ix, 0), GDIM - 1);
            int iy = (int)floorf((q[1] - pmy) / vs); iy = min(max(iy, 0), GDIM - 1);
            int iz = (int)floorf((q[2] - pmz) / vs); iz = min(max(iz, 0), GDIM - 1);
            int vid = (ix * GDIM + iy) * GDIM + iz;
            atomicOr(&bm[vid >> 5], 1u << (vid & 31));
        }
    }
    __syncthreads();

    unsigned* occ = ws + OCC_OFF + (unsigned)s * VWORDS;
    for (int w = tid; w < VWORDS; w += 256) {
        unsigned v = bm[w];
        if (v) atomicOr(&occ[w], v);
    }
}

// ---------------------------------------------------------------------------
// Greedy iteration. grid 128 blocks x 256 threads. Launched 16x (it = 0..15).
// Covered-update for iteration it-1 is folded into iteration it: every block
// ORs occ[best_prev] on the fly (idempotent => race-safe), best block persists.
// ---------------------------------------------------------------------------
__global__ __launch_bounds__(256) void iter_kernel(unsigned* __restrict__ ws,
                                                   float* __restrict__ out, int it) {
    const int s = blockIdx.x;
    const int tid = threadIdx.x;
    unsigned* occ = ws + OCC_OFF;
    unsigned* cov = ws + COV_OFF;
    unsigned* key = ws + KEY_OFF;
    unsigned* sel = ws + SEL_OFF;

    int best = -1; unsigned kprev = 0;
    if (it > 0) { kprev = key[it - 1]; best = 127 - (int)(kprev & 127u); }
    const bool isBest = (s == best);
    const bool isSel = (((sel[s >> 5] >> (s & 31)) & 1u) != 0) || isBest;
    if (isSel && !isBest) return;

    const unsigned* occS = occ + (unsigned)s * VWORDS;
    const unsigned* occB = (best >= 0) ? occ + (unsigned)best * VWORDS : nullptr;

    int g = 0;
    for (int w = tid; w < VWORDS; w += 256) {
        unsigned c = cov[w];
        if (best >= 0) c |= occB[w];
        if (isBest) cov[w] = c;                 // persist covered |= occ[best]
        if (!isSel) g += __popc(occS[w] & ~c);
    }
    if (isBest && tid == 0) {
        atomicOr(&sel[s >> 5], 1u << (s & 31));
        out[it - 1] = (float)best;              // selected index of prev iter
        out[16 + it - 1] = (float)(kprev >> 7); // its gain
    }
    if (isSel) return;

#pragma unroll
    for (int m = 32; m >= 1; m >>= 1) g += __shfl_xor(g, m);
    __shared__ int wsum[4];
    if ((tid & 63) == 0) wsum[tid >> 6] = g;
    __syncthreads();
    if (tid == 0) {
        g = wsum[0] + wsum[1] + wsum[2] + wsum[3];
        // key: max gain, then smallest s (jnp.argmax first-max tie-break)
        atomicMax(&key[it], ((unsigned)g << 7) | (unsigned)(127 - s));
    }
}

// ---------------------------------------------------------------------------
// Final: commit selection 15, total coverage. 1 block x 256
// ---------------------------------------------------------------------------
__global__ __launch_bounds__(256) void final_kernel(unsigned* __restrict__ ws,
                                                    float* __restrict__ out) {
    const int tid = threadIdx.x;
    const unsigned kp = ws[KEY_OFF + 15];
    const int best = 127 - (int)(kp & 127u);
    const unsigned* occB = ws + OCC_OFF + (unsigned)best * VWORDS;
    const unsigned* cov = ws + COV_OFF;

    int t = 0;
    for (int w = tid; w < VWORDS; w += 256) t += __popc(cov[w] | occB[w]);
#pragma unroll
    for (int m = 32; m >= 1; m >>= 1) t += __shfl_xor(t, m);
    __shared__ int wsum[4];
    if ((tid & 63) == 0) wsum[tid >> 6] = t;
    __syncthreads();
    if (tid == 0) {
        out[15] = (float)best;
        out[31] = (float)(kp >> 7);
        out[32] = (float)(wsum[0] + wsum[1] + wsum[2] + wsum[3]);
    }
}

extern "C" void kernel_launch(void* const* d_in, const int* in_sizes, int n_in,
                              void* d_out, int out_size, void* d_ws, size_t ws_size,
                              hipStream_t stream) {
    const float* wp   = (const float*)d_in[2];  // world_points [1,S,H,W,3]
    const float* conf = (const float*)d_in[3];  // world_points_conf [1,S,H,W]
    float* out = (float*)d_out;
    unsigned* ws = (unsigned*)d_ws;

    // init: zero occ+cov+keys+sel+maxU; minU sentinel = 0xFFFFFFFF
    hipMemsetAsync(ws, 0, (size_t)(MAXU_OFF + 3) * 4, stream);
    hipMemsetAsync(ws + MINU_OFF, 0xFF, 3 * 4, stream);

    float* pct = (float*)(ws + PCT_OFF);
    pct_kernel<<<128, 256, 0, stream>>>(conf, pct);
    minmax_kernel<<<dim3(7, 128), 256, 0, stream>>>(wp, conf, pct, ws);
    voxel_kernel<<<512, 256, 0, stream>>>(wp, conf, pct, ws);
    for (int it = 0; it < KSEL; it++)
        iter_kernel<<<128, 256, 0, stream>>>(ws, out, it);
    final_kernel<<<1, 256, 0, stream>>>(ws, out);
}

// Round 2
// 338.343 us; speedup vs baseline: 2.0637x; 2.0637x over previous
//
#include <hip/hip_runtime.h>
#include <hip/hip_bf16.h>
#include <cstdint>

// Problem constants
#define S_FRAMES 128
#define HW       50176            // 224*224
#define NGRP     12544            // HW/4 float4 groups per frame
#define GDIM     48
#define VWORDS   3456             // 48^3 / 32 bits
#define NBINS    4096
#define CAP      512
#define KSEL     16

// workspace layout (in 32-bit words)
#define OCC_OFF   0u                          // 128 * 3456 words
#define COV_OFF   (128u*3456u)                // 442368
#define KEY_OFF   (COV_OFF + 3456u)           // 445824: 16 words
#define SEL_OFF   (KEY_OFF + 16u)             // 445840: 4 words (128-bit selected mask)
#define MM_OFF    445856u                     // 64 slots x 16 words, 64B-aligned each
#define PCT_OFF   (MM_OFF + 64u*16u)          // 446880: 128 floats
#define WS_ZERO_WORDS PCT_OFF

__device__ __forceinline__ unsigned fkey(float f) {
    unsigned u = __float_as_uint(f);
    return (u & 0x80000000u) ? ~u : (u | 0x80000000u);
}
__device__ __forceinline__ float funkey(unsigned k) {
    unsigned u = (k & 0x80000000u) ? (k & 0x7fffffffu) : ~k;
    return __uint_as_float(u);
}

// ---------------------------------------------------------------------------
// Pass A: exact per-frame median (jnp.quantile 0.5 linear) via histogram select
// grid: 128 blocks (one per frame), 1024 threads, float4 loads both passes
// ---------------------------------------------------------------------------
__global__ __launch_bounds__(1024) void pct_kernel(const float* __restrict__ conf,
                                                   float* __restrict__ pct) {
    const int s = blockIdx.x;
    const int tid = threadIdx.x;
    const float4* c4 = (const float4*)(conf + (size_t)s * HW);

    __shared__ unsigned hist[NBINS];
    __shared__ unsigned ps[1024];
    __shared__ float    list[CAP];
    __shared__ unsigned cnt;
    __shared__ int      rbin[2];
    __shared__ unsigned rcum[2];
    __shared__ float    ab[2];

    for (int b = tid; b < NBINS; b += 1024) hist[b] = 0;
    if (tid == 0) cnt = 0;
    __syncthreads();

    for (int g = tid; g < NGRP; g += 1024) {
        float4 v = c4[g];
        int b0 = min(max((int)(v.x * 4096.0f), 0), NBINS - 1);
        int b1 = min(max((int)(v.y * 4096.0f), 0), NBINS - 1);
        int b2 = min(max((int)(v.z * 4096.0f), 0), NBINS - 1);
        int b3 = min(max((int)(v.w * 4096.0f), 0), NBINS - 1);
        atomicAdd(&hist[b0], 1u); atomicAdd(&hist[b1], 1u);
        atomicAdd(&hist[b2], 1u); atomicAdd(&hist[b3], 1u);
    }
    __syncthreads();

    // chunk sums (4 bins/thread) + inclusive scan over 1024 chunks
    unsigned chunk = hist[tid * 4] + hist[tid * 4 + 1] + hist[tid * 4 + 2] + hist[tid * 4 + 3];
    ps[tid] = chunk;
    __syncthreads();
    for (int off = 1; off < 1024; off <<= 1) {
        unsigned v = (tid >= off) ? ps[tid - off] : 0u;
        __syncthreads();
        ps[tid] += v;
        __syncthreads();
    }
    unsigned excl = ps[tid] - chunk;

    const unsigned R0 = 25087u, R1 = 25088u;  // 0.5*(50176-1) = 25087.5
#pragma unroll
    for (int r = 0; r < 2; r++) {
        unsigned rr = r ? R1 : R0;
        if (rr >= excl && rr < excl + chunk) {
            unsigned cum = excl;
            for (int j = 0; j < 4; j++) {
                unsigned h = hist[tid * 4 + j];
                if (rr < cum + h) { rbin[r] = tid * 4 + j; rcum[r] = cum; break; }
                cum += h;
            }
        }
    }
    __syncthreads();

    const int blo = rbin[0], bhi = rbin[1];
    const unsigned cumLo = rcum[0];

    for (int g = tid; g < NGRP; g += 1024) {
        float4 v = c4[g];
        float vv[4] = {v.x, v.y, v.z, v.w};
#pragma unroll
        for (int j = 0; j < 4; j++) {
            int b = min(max((int)(vv[j] * 4096.0f), 0), NBINS - 1);
            if (b >= blo && b <= bhi) {
                unsigned pos = atomicAdd(&cnt, 1u);
                if (pos < CAP) list[pos] = vv[j];
            }
        }
    }
    __syncthreads();

    const int n = (int)min(cnt, (unsigned)CAP);
    const int r0 = (int)(R0 - cumLo), r1 = (int)(R1 - cumLo);
    for (int e = tid; e < n; e += 1024) {
        float x = list[e];
        int rank = 0;
        for (int j = 0; j < n; j++) {
            float y = list[j];
            rank += (y < x) || (y == x && j < e);   // stable rank
        }
        if (rank == r0) ab[0] = x;
        if (rank == r1) ab[1] = x;
    }
    __syncthreads();
    if (tid == 0) pct[s] = 0.5f * ab[0] + 0.5f * ab[1];
}

// ---------------------------------------------------------------------------
// Pass B: global min/max over valid points. grid (49,128) x 256, 4 pts/thread.
// All-atomicMax encoding: min(x) tracked as max over fkey(-x). 64 slots of one
// cache line each to kill same-line atomic serialization.
// ---------------------------------------------------------------------------
__global__ __launch_bounds__(256) void minmax_kernel(const float* __restrict__ wp,
                                                     const float* __restrict__ conf,
                                                     const float* __restrict__ pct,
                                                     unsigned* __restrict__ ws) {
    const int s = blockIdx.y;
    const int tid = threadIdx.x;
    const int gidx = blockIdx.x * 256 + tid;        // [0, 12544)
    const float pc = pct[s];
    const size_t base = (size_t)s * HW;

    const float4 cf = ((const float4*)(conf + base))[gidx];
    const float4* wp4 = (const float4*)(wp + base * 3) + (size_t)gidx * 3;
    const float4 a = wp4[0], b = wp4[1], d = wp4[2];

    const float BIG = 3.402823466e38f;
    float mnx = BIG, mny = BIG, mnz = BIG;
    float mxx = -BIG, mxy = -BIG, mxz = -BIG;

    float px[4] = {a.x, a.w, b.z, d.y};
    float py[4] = {a.y, b.x, b.w, d.z};
    float pz[4] = {a.z, b.y, d.x, d.w};
    float cc[4] = {cf.x, cf.y, cf.z, cf.w};
#pragma unroll
    for (int j = 0; j < 4; j++) {
        bool v = (cc[j] > 0.1f) && (cc[j] >= pc);
        float x = v ? px[j] : BIG, y = v ? py[j] : BIG, z = v ? pz[j] : BIG;
        mnx = fminf(mnx, x); mny = fminf(mny, y); mnz = fminf(mnz, z);
        x = v ? px[j] : -BIG; y = v ? py[j] : -BIG; z = v ? pz[j] : -BIG;
        mxx = fmaxf(mxx, x); mxy = fmaxf(mxy, y); mxz = fmaxf(mxz, z);
    }
#pragma unroll
    for (int m = 32; m >= 1; m >>= 1) {
        mnx = fminf(mnx, __shfl_xor(mnx, m)); mny = fminf(mny, __shfl_xor(mny, m));
        mnz = fminf(mnz, __shfl_xor(mnz, m));
        mxx = fmaxf(mxx, __shfl_xor(mxx, m)); mxy = fmaxf(mxy, __shfl_xor(mxy, m));
        mxz = fmaxf(mxz, __shfl_xor(mxz, m));
    }
    __shared__ float red[4][6];
    if ((tid & 63) == 0) {
        int w = tid >> 6;
        red[w][0] = mnx; red[w][1] = mny; red[w][2] = mnz;
        red[w][3] = mxx; red[w][4] = mxy; red[w][5] = mxz;
    }
    __syncthreads();
    if (tid == 0) {
        float r0 = red[0][0], r1 = red[0][1], r2 = red[0][2];
        float r3 = red[0][3], r4 = red[0][4], r5 = red[0][5];
        for (int w = 1; w < 4; w++) {
            r0 = fminf(r0, red[w][0]); r1 = fminf(r1, red[w][1]); r2 = fminf(r2, red[w][2]);
            r3 = fmaxf(r3, red[w][3]); r4 = fmaxf(r4, red[w][4]); r5 = fmaxf(r5, red[w][5]);
        }
        unsigned* slot = ws + MM_OFF + (unsigned)((blockIdx.x + blockIdx.y * 49) & 63) * 16;
        atomicMax(slot + 0, fkey(-r0));   // min x  (as max of key(-x))
        atomicMax(slot + 1, fkey(-r1));
        atomicMax(slot + 2, fkey(-r2));
        atomicMax(slot + 3, fkey(r3));    // max x
        atomicMax(slot + 4, fkey(r4));
        atomicMax(slot + 5, fkey(r5));
    }
}

// ---------------------------------------------------------------------------
// Pass C: per-frame voxel occupancy bitmaps. grid 896 (7 blocks/frame) x 256,
// 28 points/thread via float4 loads, LDS bitmap, atomicOr merge of nonzeros.
// ---------------------------------------------------------------------------
__global__ __launch_bounds__(256) void voxel_kernel(const float* __restrict__ wp,
                                                    const float* __restrict__ conf,
                                                    const float* __restrict__ pct,
                                                    unsigned* __restrict__ ws) {
    const int bx = blockIdx.x;
    const int s = bx / 7;
    const int part = bx - s * 7;
    const int tid = threadIdx.x;

    __shared__ unsigned bm[VWORDS];
    __shared__ float prm[4];  // pmx,pmy,pmz,vs
    for (int w = tid; w < VWORDS; w += 256) bm[w] = 0;

    if (tid < 64) {
        const unsigned* sl = ws + MM_OFF + (unsigned)tid * 16;
        unsigned k0 = sl[0], k1 = sl[1], k2 = sl[2], k3 = sl[3], k4 = sl[4], k5 = sl[5];
#pragma unroll
        for (int m = 32; m >= 1; m >>= 1) {
            k0 = max(k0, (unsigned)__shfl_xor((int)k0, m));
            k1 = max(k1, (unsigned)__shfl_xor((int)k1, m));
            k2 = max(k2, (unsigned)__shfl_xor((int)k2, m));
            k3 = max(k3, (unsigned)__shfl_xor((int)k3, m));
            k4 = max(k4, (unsigned)__shfl_xor((int)k4, m));
            k5 = max(k5, (unsigned)__shfl_xor((int)k5, m));
        }
        if (tid == 0) {
            float p0 = -funkey(k0), p1 = -funkey(k1), p2 = -funkey(k2);
            float d0 = funkey(k3) - p0, d1 = funkey(k4) - p1, d2 = funkey(k5) - p2;
            prm[0] = p0; prm[1] = p1; prm[2] = p2;
            prm[3] = fminf(d0, fminf(d1, d2)) / 20.0f;   // VOXEL_LAMBDA
        }
    }
    __syncthreads();

    const float pc = pct[s];
    const float pmx = prm[0], pmy = prm[1], pmz = prm[2], vs = prm[3];
    const size_t base = (size_t)s * HW;
    const float4* c4 = (const float4*)(conf + base);
    const float4* w4 = (const float4*)(wp + base * 3);

#pragma unroll 1
    for (int k = 0; k < 7; k++) {
        int g = part * 1792 + k * 256 + tid;           // group of 4 points
        float4 cf = c4[g];
        const float4* wg = w4 + (size_t)g * 3;
        float4 a = wg[0], b = wg[1], d = wg[2];
        float px[4] = {a.x, a.w, b.z, d.y};
        float py[4] = {a.y, b.x, b.w, d.z};
        float pz[4] = {a.z, b.y, d.x, d.w};
        float cc[4] = {cf.x, cf.y, cf.z, cf.w};
#pragma unroll
        for (int j = 0; j < 4; j++) {
            if (cc[j] > 0.1f && cc[j] >= pc) {
                int ix = min(max((int)floorf((px[j] - pmx) / vs), 0), GDIM - 1);
                int iy = min(max((int)floorf((py[j] - pmy) / vs), 0), GDIM - 1);
                int iz = min(max((int)floorf((pz[j] - pmz) / vs), 0), GDIM - 1);
                int vid = (ix * GDIM + iy) * GDIM + iz;
                atomicOr(&bm[vid >> 5], 1u << (vid & 31));
            }
        }
    }
    __syncthreads();

    unsigned* occ = ws + OCC_OFF + (unsigned)s * VWORDS;
    for (int w = tid; w < VWORDS; w += 256) {
        unsigned v = bm[w];
        if (v) atomicOr(&occ[w], v);
    }
}

// ---------------------------------------------------------------------------
// Greedy iteration. grid 128 blocks x 256 threads. Launched 16x (it = 0..15).
// Covered-update for iteration it-1 is folded into iteration it.
// ---------------------------------------------------------------------------
__global__ __launch_bounds__(256) void iter_kernel(unsigned* __restrict__ ws,
                                                   float* __restrict__ out, int it) {
    const int s = blockIdx.x;
    const int tid = threadIdx.x;
    unsigned* occ = ws + OCC_OFF;
    unsigned* cov = ws + COV_OFF;
    unsigned* key = ws + KEY_OFF;
    unsigned* sel = ws + SEL_OFF;

    int best = -1; unsigned kprev = 0;
    if (it > 0) { kprev = key[it - 1]; best = 127 - (int)(kprev & 127u); }
    const bool isBest = (s == best);
    const bool isSel = (((sel[s >> 5] >> (s & 31)) & 1u) != 0) || isBest;
    if (isSel && !isBest) return;

    const unsigned* occS = occ + (unsigned)s * VWORDS;
    const unsigned* occB = (best >= 0) ? occ + (unsigned)best * VWORDS : nullptr;

    int g = 0;
    for (int w = tid; w < VWORDS; w += 256) {
        unsigned c = cov[w];
        if (best >= 0) c |= occB[w];
        if (isBest) cov[w] = c;                 // persist covered |= occ[best]
        if (!isSel) g += __popc(occS[w] & ~c);
    }
    if (isBest && tid == 0) {
        atomicOr(&sel[s >> 5], 1u << (s & 31));
        out[it - 1] = (float)best;              // selected index of prev iter
        out[16 + it - 1] = (float)(kprev >> 7); // its gain
    }
    if (isSel) return;

#pragma unroll
    for (int m = 32; m >= 1; m >>= 1) g += __shfl_xor(g, m);
    __shared__ int wsum[4];
    if ((tid & 63) == 0) wsum[tid >> 6] = g;
    __syncthreads();
    if (tid == 0) {
        g = wsum[0] + wsum[1] + wsum[2] + wsum[3];
        // key: max gain, then smallest s (jnp.argmax first-max tie-break)
        atomicMax(&key[it], ((unsigned)g << 7) | (unsigned)(127 - s));
    }
}

// ---------------------------------------------------------------------------
// Final: commit selection 15, total coverage. 1 block x 256
// ---------------------------------------------------------------------------
__global__ __launch_bounds__(256) void final_kernel(unsigned* __restrict__ ws,
                                                    float* __restrict__ out) {
    const int tid = threadIdx.x;
    const unsigned kp = ws[KEY_OFF + 15];
    const int best = 127 - (int)(kp & 127u);
    const unsigned* occB = ws + OCC_OFF + (unsigned)best * VWORDS;
    const unsigned* cov = ws + COV_OFF;

    int t = 0;
    for (int w = tid; w < VWORDS; w += 256) t += __popc(cov[w] | occB[w]);
#pragma unroll
    for (int m = 32; m >= 1; m >>= 1) t += __shfl_xor(t, m);
    __shared__ int wsum[4];
    if ((tid & 63) == 0) wsum[tid >> 6] = t;
    __syncthreads();
    if (tid == 0) {
        out[15] = (float)best;
        out[31] = (float)(kp >> 7);
        out[32] = (float)(wsum[0] + wsum[1] + wsum[2] + wsum[3]);
    }
}

extern "C" void kernel_launch(void* const* d_in, const int* in_sizes, int n_in,
                              void* d_out, int out_size, void* d_ws, size_t ws_size,
                              hipStream_t stream) {
    const float* wp   = (const float*)d_in[2];  // world_points [1,S,H,W,3]
    const float* conf = (const float*)d_in[3];  // world_points_conf [1,S,H,W]
    float* out = (float*)d_out;
    unsigned* ws = (unsigned*)d_ws;

    // zero occ + cov + keys + sel + minmax slots (all max-encoded, 0 = -inf key)
    hipMemsetAsync(ws, 0, (size_t)WS_ZERO_WORDS * 4, stream);

    float* pct = (float*)(ws + PCT_OFF);
    pct_kernel<<<128, 1024, 0, stream>>>(conf, pct);
    minmax_kernel<<<dim3(49, 128), 256, 0, stream>>>(wp, conf, pct, ws);
    voxel_kernel<<<896, 256, 0, stream>>>(wp, conf, pct, ws);
    for (int it = 0; it < KSEL; it++)
        iter_kernel<<<128, 256, 0, stream>>>(ws, out, it);
    final_kernel<<<1, 256, 0, stream>>>(ws, out);
}